// Round 20
// baseline (22.076 us; speedup 1.0000x reference)
//
#include <hip/hip_runtime.h>
#include <math.h>

#define NL     512      // EH*EW = 16*32
#define EH_C   16
#define EW_C   32
#define P_PTS  8192
#define PT_PTS 65536
#define PROW   33       // probe tile row stride (col 32 = col 0 dup)
#define PTILE  (17*33)  // 561; row 16 = row 15 dup
#define RBLK   512      // blocks; each renders 16 points (8 waves x 2) + 128 bg rows

typedef float f32x2 __attribute__((ext_vector_type(2)));

__device__ __forceinline__ float rcp_f(float x)  { return __builtin_amdgcn_rcpf(x); }
__device__ __forceinline__ float rsq_f(float x)  { return __builtin_amdgcn_rsqf(x); }
__device__ __forceinline__ float sqrt_f(float x) { return __builtin_amdgcn_sqrtf(x); }

__device__ __forceinline__ f32x2 rcp2(f32x2 x)  { return (f32x2){rcp_f(x.x),  rcp_f(x.y)}; }
__device__ __forceinline__ f32x2 rsq2(f32x2 x)  { return (f32x2){rsq_f(x.x),  rsq_f(x.y)}; }
__device__ __forceinline__ f32x2 sqrt2(f32x2 x) { return (f32x2){sqrt_f(x.x), sqrt_f(x.y)}; }
__device__ __forceinline__ f32x2 floor2(f32x2 x){ return (f32x2){floorf(x.x), floorf(x.y)}; }
__device__ __forceinline__ f32x2 abs2(f32x2 x)  { return (f32x2){fabsf(x.x),  fabsf(x.y)}; }
__device__ __forceinline__ f32x2 max2(f32x2 a, f32x2 b){ return (f32x2){fmaxf(a.x,b.x), fmaxf(a.y,b.y)}; }
__device__ __forceinline__ f32x2 min2(f32x2 a, f32x2 b){ return (f32x2){fminf(a.x,b.x), fminf(a.y,b.y)}; }
__device__ __forceinline__ f32x2 maxs(f32x2 a, float b){ return (f32x2){fmaxf(a.x,b), fmaxf(a.y,b)}; }

// normalize helper: inv = 1/(|v|+eps) via rsq+rcp (approx, ~1e-7 rel)
__device__ __forceinline__ float inv_len_eps(float xx) {
    float len = xx * rsq_f(fmaxf(xx, 1e-30f));   // |v| = v2 * rsqrt(v2)
    return rcp_f(len + 1e-8f);
}

// 512 blocks x 512 threads. Each block: 8 waves x 2 sequential points = 16 points,
// plus 128 background rows (threads <128 at END; rows NOT in inds -> disjoint writes).
// (512,4): VGPR cap 128. Lessons: unroll of 2-pt loop regresses (R18); f16 texels
// regress (R16/R9); 8-wave bound spills (R13); deg-3 acos / deg-9 atan2 have the
// SAME absmax 0.01367 as higher-degree (R6-R8) -> use the cheap ones.
__global__ __launch_bounds__(512, 4) void fused_kernel(
    const float* __restrict__ surf,      // P,3
    const float* __restrict__ ray_o,     // P,3
    const float* __restrict__ norm_raw,  // P,3
    const float* __restrict__ albedo,    // P,3
    const float* __restrict__ rough,     // P,1
    const float* __restrict__ lvis,      // P,512
    const float* __restrict__ xyz,       // 512,3
    const float* __restrict__ area,      // 512
    const float* __restrict__ probe,     // 512,3
    const float* __restrict__ grd_rgb,   // Pt,3
    const float* __restrict__ grd_acc,   // Pt
    const int*   __restrict__ inds,      // P (sorted)
    float* __restrict__ out)             // Pt,3
{
    __shared__ float4 sA[NL];     // xyz.xyz, w = area/(|xyz|+1e-8)   (8 KB)
    __shared__ float4 sP2[PTILE]; // probe rgb f32, border-dup [17][33] (9 KB)

    {
        int i = threadIdx.x;      // NL == 512 == blockDim -> exactly one element
        float x = xyz[3*i+0], y = xyz[3*i+1], z = xyz[3*i+2];
        float aw = area[i] / (sqrtf(x*x + y*y + z*z) + 1e-8f);
        sA[i] = make_float4(x, y, z, aw);
    }
    for (int i = threadIdx.x; i < PTILE; i += 512) {
        int vr = i / PROW;               // const-divisor -> magic mul
        int ur = i - vr * PROW;
        int sv = vr > 15 ? 15 : vr;      // row 16 -> 15 (v clamp dup)
        int su = ur & 31;                // col 32 -> 0 (u wrap dup)
        int t  = 3 * (sv * EW_C + su);
        sP2[i] = make_float4(probe[t], probe[t+1], probe[t+2], 0.0f);
    }
    __syncthreads();

    const int lane  = threadIdx.x & 63;
    const int pbase = blockIdx.x * 16 + ((threadIdx.x >> 6) << 1);

    // Two sequential points per wave; unroll disabled so registers are REUSED.
    #pragma clang loop unroll(disable)
    for (int sub = 0; sub < 2; ++sub) {
        const int p = pbase + sub;

        // ---- per-point precompute (approx rsq/rcp normalization) ----
        float sx = surf[3*p+0], sy = surf[3*p+1], sz = surf[3*p+2];
        float nx = norm_raw[3*p+0], ny = norm_raw[3*p+1], nz = norm_raw[3*p+2];
        { float inv = inv_len_eps(nx*nx + ny*ny + nz*nz); nx*=inv; ny*=inv; nz*=inv; }
        float cx = ray_o[3*p+0]-sx, cy = ray_o[3*p+1]-sy, cz = ray_o[3*p+2]-sz;
        { float inv = inv_len_eps(cx*cx + cy*cy + cz*cz); cx*=inv; cy*=inv; cz*=inv; }

        float cos_v  = nx*cx + ny*cy + nz*cz;
        float sdn    = sx*nx + sy*ny + sz*nz;     // s.n (for ldn identity)
        float r      = rough[p];
        float alpha2 = (r*r)*(r*r);
        float cvsq   = fminf(fmaxf(cos_v*cos_v, 0.0f), 1.0f);
        float tvsq   = (cvsq > 1e-12f) ? fminf((1.0f - cvsq) * rcp_f(cvsq), 1e10f) : 0.0f;
        float gden   = 1.0f + sqrt_f(1.0f + alpha2 * tvsq);
        // chi_g == (cos_v > 0) since l.h >= 0 always; |cos_v|<=1e-12 edge folded in.
        float g2a    = (cos_v > 1e-12f) ? 2.0f * rcp_f(gden) * alpha2 * 0.3183098862f : 0.0f;
        float a2m1   = alpha2 - 1.0f;
        float acv4   = 4.0f * fabsf(cos_v);
        float ab0 = albedo[3*p+0] * 0.3183098862f;
        float ab1 = albedo[3*p+1] * 0.3183098862f;
        float ab2 = albedo[3*p+2] * 0.3183098862f;
        const float* lv = lvis + p*NL;

        f32x2 acc0 = (f32x2)(0.0f), acc1 = (f32x2)(0.0f), acc2 = (f32x2)(0.0f);

        #pragma unroll
        for (int it = 0; it < 4; ++it) {
            int l0 = it*128 + (lane << 1);          // lights l0, l0+1 (adjacent)
            float2 lvv = *reinterpret_cast<const float2*>(lv + l0);   // one 8B load
            float4 A0 = sA[l0], A1 = sA[l0+1];
            f32x2 Ax = {A0.x, A1.x}, Ay = {A0.y, A1.y}, Az = {A0.z, A1.z}, Aw = {A0.w, A1.w};

            // surf2light (|d| ~ O(10): no zero guard needed)
            f32x2 dx = Ax - sx, dy = Ay - sy, dz = Az - sz;
            f32x2 inv = rsq2(dx*dx + dy*dy + dz*dz);
            f32x2 slx = dx*inv, sly = dy*inv, slz = dz*inv;

            // sh = lvis * (n . xyz) * (area/|xyz|) ; ldraw = A.n reused for ldn
            f32x2 ldraw = Ax*nx + Ay*ny + Az*nz;
            f32x2 sh = ((f32x2){lvv.x, lvv.y}) * ldraw * Aw;

            // ---- v = acos(zc)*K - 0.5 ; deg-3 A&S 4.4.45, K=16/pi prescaled
            //      (absmax identical to deg-7 — R6-R8 measurements) ----
            f32x2 zc = min2(maxs(slz, -0.999999f), (f32x2)(0.999999f));
            f32x2 xa = abs2(zc);
            f32x2 pcl = ((xa*-0.0953875f + 0.378208f)*xa - 1.0802913f)*xa + 7.9996562f;
            f32x2 vpre = sqrt2(1.0f - xa) * pcl;              // acos(|zc|)*K
            f32x2 vv;
            vv.x = (zc.x < 0.0f) ? (15.5f - vpre.x) : (vpre.x - 0.5f);
            vv.y = (zc.y < 0.0f) ? (15.5f - vpre.y) : (vpre.y - 0.5f);

            // ---- u = atan2(sly,slx)*K + 15.5 ; deg-9 odd minimax, K folded.
            // Quadrant constants exact in u-units: K*pi/2 = 8, K*pi = 16.
            f32x2 axv = abs2(slx), ayv = abs2(sly);
            f32x2 mx = max2(axv, ayv), mn = min2(axv, ayv);
            f32x2 a  = mn * rcp2(maxs(mx, 1e-37f));
            f32x2 s  = a * a;
            f32x2 pu = (((s*0.106112f - 0.433578f)*s + 0.917450f)*s - 1.682201f)*s + 5.0922757f;
            f32x2 rk = a * pu;                                 // atan(a)*K
            rk.x = (ayv.x > axv.x) ? 8.0f  - rk.x : rk.x;
            rk.y = (ayv.y > axv.y) ? 8.0f  - rk.y : rk.y;
            rk.x = (slx.x < 0.0f)  ? 16.0f - rk.x : rk.x;
            rk.y = (slx.y < 0.0f)  ? 16.0f - rk.y : rk.y;
            f32x2 uu = { copysignf(rk.x, sly.x) + 15.5f,
                         copysignf(rk.y, sly.y) + 15.5f };

            // ---- bilinear weights ----
            f32x2 v0f = floor2(vv), u0f = floor2(uu);
            f32x2 fv = vv - v0f, fu = uu - u0f;
            f32x2 w11 = fu*fv, w10 = fv - w11, w01 = fu - w11;
            f32x2 w00 = (1.0f - fu) - w10;

            // ---- microfacet: |h|^2=2+2hdot; ldh=(1+hdot)/|h|; cm=(ldn+cos_v)/|h|
            //      ldn = s2l.n = inv*(A.n - s.n)  (linearity; ldraw reused) ----
            f32x2 hdot = slx*cx + sly*cy + slz*cz;
            f32x2 ih   = rsq2(maxs(hdot*2.0f + 2.0f, 1e-12f));
            f32x2 ldh  = (1.0f + hdot) * ih;
            f32x2 ldn  = (ldraw - sdn) * inv;
            f32x2 cm   = (ldn + cos_v) * ih;
            f32x2 om   = 1.0f - ldh;
            f32x2 om2  = om*om;
            f32x2 ff   = om2*om2*om*0.09f + 0.91f;
            f32x2 q    = cm*cm*a2m1 + 1.0f;                    // cm^4*(a2+tan^2m) collapsed
            f32x2 den  = abs2(ldn) * acv4;
            f32x2 micro = ff * g2a * rcp2(q*q*den);            // single rcp for D and 1/den
            micro.x = (cm.x > 1e-6f && den.x > 1e-12f) ? micro.x : 0.0f;
            micro.y = (cm.y > 1e-6f && den.y > 1e-12f) ? micro.y : 0.0f;

            // ---- probe gathers: ONE address per light; +1/+PROW/+PROW+1 imm offsets ----
            int v0a = (int)v0f.x; v0a = v0a < 0 ? 0 : v0a;     // v <= 15.5 -> floor <= 15
            int u0a = ((int)u0f.x) & 31;                       // floor(u) in [-1,31]; -1 -> 31 ok
            int v0b = (int)v0f.y; v0b = v0b < 0 ? 0 : v0b;
            int u0b = ((int)u0f.y) & 31;
            const float4* pa = &sP2[v0a*PROW + u0a];
            const float4* pb = &sP2[v0b*PROW + u0b];
            float4 t00a = pa[0], t01a = pa[1], t10a = pa[PROW], t11a = pa[PROW+1];
            float4 t00b = pb[0], t01b = pb[1], t10b = pb[PROW], t11b = pb[PROW+1];

            f32x2 li0 = { fmaf(t00a.x,w00.x, fmaf(t01a.x,w01.x, fmaf(t10a.x,w10.x, t11a.x*w11.x))),
                          fmaf(t00b.x,w00.y, fmaf(t01b.x,w01.y, fmaf(t10b.x,w10.y, t11b.x*w11.y))) };
            f32x2 li1 = { fmaf(t00a.y,w00.x, fmaf(t01a.y,w01.x, fmaf(t10a.y,w10.x, t11a.y*w11.x))),
                          fmaf(t00b.y,w00.y, fmaf(t01b.y,w01.y, fmaf(t10b.y,w10.y, t11b.y*w11.y))) };
            f32x2 li2 = { fmaf(t00a.z,w00.x, fmaf(t01a.z,w01.x, fmaf(t10a.z,w10.x, t11a.z*w11.x))),
                          fmaf(t00b.z,w00.y, fmaf(t01b.z,w01.y, fmaf(t10b.z,w10.y, t11b.z*w11.y))) };

            acc0 += (micro + ab0) * (sh * li0);
            acc1 += (micro + ab1) * (sh * li1);
            acc2 += (micro + ab2) * (sh * li2);
        }

        float c0 = acc0.x + acc0.y;
        float c1 = acc1.x + acc1.y;
        float c2 = acc2.x + acc2.y;

        // wave64 butterfly reduce
        for (int off = 32; off > 0; off >>= 1) {
            c0 += __shfl_xor(c0, off);
            c1 += __shfl_xor(c1, off);
            c2 += __shfl_xor(c2, off);
        }

        if (lane == 0) {
            int idx = inds[p];
            // numpy scatter-set: last write wins; inds sorted -> only last occurrence writes
            bool last = (p == P_PTS-1) || (inds[p+1] != idx);
            if (last) {
                float a = grd_acc[idx];
                float rgb[3] = {c0, c1, c2};
                #pragma unroll
                for (int c = 0; c < 3; ++c) {
                    float x = fminf(fmaxf(rgb[c], 0.0f), 1.0f);
                    float sr = (x <= 0.0031308f)
                             ? 12.92f * x
                             : fmaf(1.055f, exp2f(log2f(x) * (1.0f/2.4f)), -0.055f);
                    out[3*idx+c] = fmaf(grd_rgb[3*idx+c], a, sr * (1.0f - a));
                }
            }
        }
    }

    // ---- background rows for this block (threads <128; rows NOT in inds) ----
    if (threadIdx.x < 128) {
        int row = blockIdx.x * 128 + threadIdx.x;     // 512*128 = 65536 rows
        int lo = 0, hi = P_PTS;
        while (lo < hi) { int mid = (lo + hi) >> 1; if (inds[mid] < row) lo = mid + 1; else hi = mid; }
        bool scattered = (lo < P_PTS) && (inds[lo] == row);
        if (!scattered) {
            float a = grd_acc[row];
            out[3*row+0] = grd_rgb[3*row+0] * a;
            out[3*row+1] = grd_rgb[3*row+1] * a;
            out[3*row+2] = grd_rgb[3*row+2] * a;
        }
    }
}

extern "C" void kernel_launch(void* const* d_in, const int* in_sizes, int n_in,
                              void* d_out, int out_size, void* d_ws, size_t ws_size,
                              hipStream_t stream) {
    const float* surf      = (const float*)d_in[0];
    const float* ray_o     = (const float*)d_in[1];
    const float* norm_raw  = (const float*)d_in[2];
    const float* albedo    = (const float*)d_in[3];
    const float* roughness = (const float*)d_in[4];
    const float* lvis      = (const float*)d_in[5];
    const float* xyz       = (const float*)d_in[6];
    const float* area      = (const float*)d_in[7];
    const float* probe     = (const float*)d_in[8];
    const float* grd_rgb   = (const float*)d_in[9];
    const float* grd_acc   = (const float*)d_in[10];
    const int*   inds      = (const int*)d_in[11];
    float* out = (float*)d_out;

    fused_kernel<<<RBLK, 512, 0, stream>>>(surf, ray_o, norm_raw,
        albedo, roughness, lvis, xyz, area, probe, grd_rgb, grd_acc, inds, out);
}

// Round 21
// 21.446 us; speedup vs baseline: 1.0293x; 1.0293x over previous
//
#include <hip/hip_runtime.h>
#include <math.h>

#define NL     512      // EH*EW = 16*32
#define EH_C   16
#define EW_C   32
#define P_PTS  8192
#define PT_PTS 65536
#define PROW   33       // probe tile row stride (col 32 = col 0 dup)
#define PTILE  (17*33)  // 561; row 16 = row 15 dup
#define RBLK   512      // blocks; each renders 16 points (8 waves x 2) + 128 bg rows

typedef float f32x2 __attribute__((ext_vector_type(2)));

__device__ __forceinline__ float rcp_f(float x)  { return __builtin_amdgcn_rcpf(x); }
__device__ __forceinline__ float rsq_f(float x)  { return __builtin_amdgcn_rsqf(x); }
__device__ __forceinline__ float sqrt_f(float x) { return __builtin_amdgcn_sqrtf(x); }

__device__ __forceinline__ f32x2 rcp2(f32x2 x)  { return (f32x2){rcp_f(x.x),  rcp_f(x.y)}; }
__device__ __forceinline__ f32x2 rsq2(f32x2 x)  { return (f32x2){rsq_f(x.x),  rsq_f(x.y)}; }
__device__ __forceinline__ f32x2 sqrt2(f32x2 x) { return (f32x2){sqrt_f(x.x), sqrt_f(x.y)}; }
__device__ __forceinline__ f32x2 floor2(f32x2 x){ return (f32x2){floorf(x.x), floorf(x.y)}; }
__device__ __forceinline__ f32x2 abs2(f32x2 x)  { return (f32x2){fabsf(x.x),  fabsf(x.y)}; }
__device__ __forceinline__ f32x2 max2(f32x2 a, f32x2 b){ return (f32x2){fmaxf(a.x,b.x), fmaxf(a.y,b.y)}; }
__device__ __forceinline__ f32x2 min2(f32x2 a, f32x2 b){ return (f32x2){fminf(a.x,b.x), fminf(a.y,b.y)}; }
__device__ __forceinline__ f32x2 maxs(f32x2 a, float b){ return (f32x2){fmaxf(a.x,b), fmaxf(a.y,b)}; }

// normalize helper: inv = 1/(|v|+eps) via rsq+rcp (approx, ~1e-7 rel; matches
// the loop's approx-op policy; replaces ~15-instr IEEE divide chains)
__device__ __forceinline__ float inv_len_eps(float xx) {
    float len = xx * rsq_f(fmaxf(xx, 1e-30f));   // |v| = v2 * rsqrt(v2)
    return rcp_f(len + 1e-8f);
}

// 512 blocks x 512 threads. Each block: 8 waves x 2 sequential points = 16 points,
// plus 128 background rows (threads <128 at END; rows NOT in inds -> disjoint writes).
// (512,4): VGPR cap 128. Final config = best measured (R19, 21.58us). Lessons:
// unrolling the 2-pt loop regresses (R18); f16 texels regress (R16/R9); 8-wave
// bound spills (R13); shorter polys / ldn identity regress ~2% (R20).
__global__ __launch_bounds__(512, 4) void fused_kernel(
    const float* __restrict__ surf,      // P,3
    const float* __restrict__ ray_o,     // P,3
    const float* __restrict__ norm_raw,  // P,3
    const float* __restrict__ albedo,    // P,3
    const float* __restrict__ rough,     // P,1
    const float* __restrict__ lvis,      // P,512
    const float* __restrict__ xyz,       // 512,3
    const float* __restrict__ area,      // 512
    const float* __restrict__ probe,     // 512,3
    const float* __restrict__ grd_rgb,   // Pt,3
    const float* __restrict__ grd_acc,   // Pt
    const int*   __restrict__ inds,      // P (sorted)
    float* __restrict__ out)             // Pt,3
{
    __shared__ float4 sA[NL];     // xyz.xyz, w = area/(|xyz|+1e-8)   (8 KB)
    __shared__ float4 sP2[PTILE]; // probe rgb f32, border-dup [17][33] (9 KB)

    {
        int i = threadIdx.x;      // NL == 512 == blockDim -> exactly one element
        float x = xyz[3*i+0], y = xyz[3*i+1], z = xyz[3*i+2];
        float aw = area[i] / (sqrtf(x*x + y*y + z*z) + 1e-8f);
        sA[i] = make_float4(x, y, z, aw);
    }
    for (int i = threadIdx.x; i < PTILE; i += 512) {
        int vr = i / PROW;               // const-divisor -> magic mul
        int ur = i - vr * PROW;
        int sv = vr > 15 ? 15 : vr;      // row 16 -> 15 (v clamp dup)
        int su = ur & 31;                // col 32 -> 0 (u wrap dup)
        int t  = 3 * (sv * EW_C + su);
        sP2[i] = make_float4(probe[t], probe[t+1], probe[t+2], 0.0f);
    }
    __syncthreads();

    const int lane  = threadIdx.x & 63;
    const int pbase = blockIdx.x * 16 + ((threadIdx.x >> 6) << 1);

    // Two sequential points per wave; unroll disabled so registers are REUSED.
    #pragma clang loop unroll(disable)
    for (int sub = 0; sub < 2; ++sub) {
        const int p = pbase + sub;

        // ---- per-point precompute (approx rsq/rcp normalization) ----
        float sx = surf[3*p+0], sy = surf[3*p+1], sz = surf[3*p+2];
        float nx = norm_raw[3*p+0], ny = norm_raw[3*p+1], nz = norm_raw[3*p+2];
        { float inv = inv_len_eps(nx*nx + ny*ny + nz*nz); nx*=inv; ny*=inv; nz*=inv; }
        float cx = ray_o[3*p+0]-sx, cy = ray_o[3*p+1]-sy, cz = ray_o[3*p+2]-sz;
        { float inv = inv_len_eps(cx*cx + cy*cy + cz*cz); cx*=inv; cy*=inv; cz*=inv; }

        float cos_v  = nx*cx + ny*cy + nz*cz;
        float r      = rough[p];
        float alpha2 = (r*r)*(r*r);
        float cvsq   = fminf(fmaxf(cos_v*cos_v, 0.0f), 1.0f);
        float tvsq   = (cvsq > 1e-12f) ? fminf((1.0f - cvsq) * rcp_f(cvsq), 1e10f) : 0.0f;
        float gden   = 1.0f + sqrt_f(1.0f + alpha2 * tvsq);
        // chi_g == (cos_v > 0) since l.h >= 0 always; |cos_v|<=1e-12 edge folded in.
        float g2a    = (cos_v > 1e-12f) ? 2.0f * rcp_f(gden) * alpha2 * 0.3183098862f : 0.0f;
        float a2m1   = alpha2 - 1.0f;
        float acv4   = 4.0f * fabsf(cos_v);
        float ab0 = albedo[3*p+0] * 0.3183098862f;
        float ab1 = albedo[3*p+1] * 0.3183098862f;
        float ab2 = albedo[3*p+2] * 0.3183098862f;
        const float* lv = lvis + p*NL;

        f32x2 acc0 = (f32x2)(0.0f), acc1 = (f32x2)(0.0f), acc2 = (f32x2)(0.0f);

        #pragma unroll
        for (int it = 0; it < 4; ++it) {
            int l0 = it*128 + (lane << 1);          // lights l0, l0+1 (adjacent)
            float2 lvv = *reinterpret_cast<const float2*>(lv + l0);   // one 8B load
            float4 A0 = sA[l0], A1 = sA[l0+1];
            f32x2 Ax = {A0.x, A1.x}, Ay = {A0.y, A1.y}, Az = {A0.z, A1.z}, Aw = {A0.w, A1.w};

            // surf2light (|d| ~ O(10): no zero guard needed)
            f32x2 dx = Ax - sx, dy = Ay - sy, dz = Az - sz;
            f32x2 inv = rsq2(dx*dx + dy*dy + dz*dz);
            f32x2 slx = dx*inv, sly = dy*inv, slz = dz*inv;

            // sh = lvis * (n . xyz) * (area/|xyz|)
            f32x2 sh = ((f32x2){lvv.x, lvv.y}) * (Ax*nx + Ay*ny + Az*nz) * Aw;

            // ---- v = acos(zc)*K - 0.5 ; A&S 4.4.46 deg-7, K=16/pi prescaled ----
            f32x2 zc = min2(maxs(slz, -0.999999f), (f32x2)(0.999999f));
            f32x2 xa = abs2(zc);
            f32x2 pcl = xa*-0.00642982f + 0.03397049f;
            pcl = pcl*xa - 0.08702911f;
            pcl = pcl*xa + 0.15733105f;
            pcl = pcl*xa - 0.25553564f;
            pcl = pcl*xa + 0.45316427f;
            pcl = pcl*xa - 1.09294280f;
            pcl = pcl*xa + 7.99999960f;
            f32x2 vpre = sqrt2(1.0f - xa) * pcl;              // acos(|zc|)*K
            f32x2 vv;
            vv.x = (zc.x < 0.0f) ? (15.5f - vpre.x) : (vpre.x - 0.5f);
            vv.y = (zc.y < 0.0f) ? (15.5f - vpre.y) : (vpre.y - 0.5f);

            // ---- u = atan2(sly,slx)*K + 15.5 ; deg-11 odd minimax, K folded.
            // Quadrant constants exact in u-units: K*pi/2 = 8, K*pi = 16.
            f32x2 axv = abs2(slx), ayv = abs2(sly);
            f32x2 mx = max2(axv, ayv), mn = min2(axv, ayv);
            f32x2 a  = mn * rcp2(maxs(mx, 1e-37f));
            f32x2 s  = a * a;
            f32x2 pu = s*-0.0596956f + 0.2681612f;
            pu = pu*s - 0.5929877f;
            pu = pu*s + 0.9857085f;
            pu = pu*s - 1.6940397f;
            pu = pu*s + 5.0928424f;
            f32x2 rk = a * pu;                                 // atan(a)*K
            rk.x = (ayv.x > axv.x) ? 8.0f  - rk.x : rk.x;
            rk.y = (ayv.y > axv.y) ? 8.0f  - rk.y : rk.y;
            rk.x = (slx.x < 0.0f)  ? 16.0f - rk.x : rk.x;
            rk.y = (slx.y < 0.0f)  ? 16.0f - rk.y : rk.y;
            f32x2 uu = { copysignf(rk.x, sly.x) + 15.5f,
                         copysignf(rk.y, sly.y) + 15.5f };

            // ---- bilinear weights ----
            f32x2 v0f = floor2(vv), u0f = floor2(uu);
            f32x2 fv = vv - v0f, fu = uu - u0f;
            f32x2 w11 = fu*fv, w10 = fv - w11, w01 = fu - w11;
            f32x2 w00 = (1.0f - fu) - w10;

            // ---- microfacet: |h|^2=2+2hdot; ldh=(1+hdot)/|h|; cm=(ldn+cos_v)/|h| ----
            f32x2 hdot = slx*cx + sly*cy + slz*cz;
            f32x2 ih   = rsq2(maxs(hdot*2.0f + 2.0f, 1e-12f));
            f32x2 ldh  = (1.0f + hdot) * ih;
            f32x2 ldn  = slx*nx + sly*ny + slz*nz;
            f32x2 cm   = (ldn + cos_v) * ih;
            f32x2 om   = 1.0f - ldh;
            f32x2 om2  = om*om;
            f32x2 ff   = om2*om2*om*0.09f + 0.91f;
            f32x2 q    = cm*cm*a2m1 + 1.0f;                    // cm^4*(a2+tan^2m) collapsed
            f32x2 den  = abs2(ldn) * acv4;
            f32x2 micro = ff * g2a * rcp2(q*q*den);            // single rcp for D and 1/den
            micro.x = (cm.x > 1e-6f && den.x > 1e-12f) ? micro.x : 0.0f;
            micro.y = (cm.y > 1e-6f && den.y > 1e-12f) ? micro.y : 0.0f;

            // ---- probe gathers: ONE address per light; +1/+PROW/+PROW+1 imm offsets ----
            int v0a = (int)v0f.x; v0a = v0a < 0 ? 0 : v0a;     // v <= 15.5 -> floor <= 15
            int u0a = ((int)u0f.x) & 31;                       // floor(u) in [-1,31]; -1 -> 31 ok
            int v0b = (int)v0f.y; v0b = v0b < 0 ? 0 : v0b;
            int u0b = ((int)u0f.y) & 31;
            const float4* pa = &sP2[v0a*PROW + u0a];
            const float4* pb = &sP2[v0b*PROW + u0b];
            float4 t00a = pa[0], t01a = pa[1], t10a = pa[PROW], t11a = pa[PROW+1];
            float4 t00b = pb[0], t01b = pb[1], t10b = pb[PROW], t11b = pb[PROW+1];

            f32x2 li0 = { fmaf(t00a.x,w00.x, fmaf(t01a.x,w01.x, fmaf(t10a.x,w10.x, t11a.x*w11.x))),
                          fmaf(t00b.x,w00.y, fmaf(t01b.x,w01.y, fmaf(t10b.x,w10.y, t11b.x*w11.y))) };
            f32x2 li1 = { fmaf(t00a.y,w00.x, fmaf(t01a.y,w01.x, fmaf(t10a.y,w10.x, t11a.y*w11.x))),
                          fmaf(t00b.y,w00.y, fmaf(t01b.y,w01.y, fmaf(t10b.y,w10.y, t11b.y*w11.y))) };
            f32x2 li2 = { fmaf(t00a.z,w00.x, fmaf(t01a.z,w01.x, fmaf(t10a.z,w10.x, t11a.z*w11.x))),
                          fmaf(t00b.z,w00.y, fmaf(t01b.z,w01.y, fmaf(t10b.z,w10.y, t11b.z*w11.y))) };

            acc0 += (micro + ab0) * (sh * li0);
            acc1 += (micro + ab1) * (sh * li1);
            acc2 += (micro + ab2) * (sh * li2);
        }

        float c0 = acc0.x + acc0.y;
        float c1 = acc1.x + acc1.y;
        float c2 = acc2.x + acc2.y;

        // wave64 butterfly reduce
        for (int off = 32; off > 0; off >>= 1) {
            c0 += __shfl_xor(c0, off);
            c1 += __shfl_xor(c1, off);
            c2 += __shfl_xor(c2, off);
        }

        if (lane == 0) {
            int idx = inds[p];
            // numpy scatter-set: last write wins; inds sorted -> only last occurrence writes
            bool last = (p == P_PTS-1) || (inds[p+1] != idx);
            if (last) {
                float a = grd_acc[idx];
                float rgb[3] = {c0, c1, c2};
                #pragma unroll
                for (int c = 0; c < 3; ++c) {
                    float x = fminf(fmaxf(rgb[c], 0.0f), 1.0f);
                    float sr = (x <= 0.0031308f)
                             ? 12.92f * x
                             : fmaf(1.055f, exp2f(log2f(x) * (1.0f/2.4f)), -0.055f);
                    out[3*idx+c] = fmaf(grd_rgb[3*idx+c], a, sr * (1.0f - a));
                }
            }
        }
    }

    // ---- background rows for this block (threads <128; rows NOT in inds) ----
    if (threadIdx.x < 128) {
        int row = blockIdx.x * 128 + threadIdx.x;     // 512*128 = 65536 rows
        int lo = 0, hi = P_PTS;
        while (lo < hi) { int mid = (lo + hi) >> 1; if (inds[mid] < row) lo = mid + 1; else hi = mid; }
        bool scattered = (lo < P_PTS) && (inds[lo] == row);
        if (!scattered) {
            float a = grd_acc[row];
            out[3*row+0] = grd_rgb[3*row+0] * a;
            out[3*row+1] = grd_rgb[3*row+1] * a;
            out[3*row+2] = grd_rgb[3*row+2] * a;
        }
    }
}

extern "C" void kernel_launch(void* const* d_in, const int* in_sizes, int n_in,
                              void* d_out, int out_size, void* d_ws, size_t ws_size,
                              hipStream_t stream) {
    const float* surf      = (const float*)d_in[0];
    const float* ray_o     = (const float*)d_in[1];
    const float* norm_raw  = (const float*)d_in[2];
    const float* albedo    = (const float*)d_in[3];
    const float* roughness = (const float*)d_in[4];
    const float* lvis      = (const float*)d_in[5];
    const float* xyz       = (const float*)d_in[6];
    const float* area      = (const float*)d_in[7];
    const float* probe     = (const float*)d_in[8];
    const float* grd_rgb   = (const float*)d_in[9];
    const float* grd_acc   = (const float*)d_in[10];
    const int*   inds      = (const int*)d_in[11];
    float* out = (float*)d_out;

    fused_kernel<<<RBLK, 512, 0, stream>>>(surf, ray_o, norm_raw,
        albedo, roughness, lvis, xyz, area, probe, grd_rgb, grd_acc, inds, out);
}